// Round 6
// baseline (219.944 us; speedup 1.0000x reference)
//
#include <hip/hip_runtime.h>
#include <hip/hip_bf16.h>

typedef __hip_bfloat16 bf16;
typedef unsigned int u32;
typedef unsigned short u16;
typedef __attribute__((ext_vector_type(8))) short bf16x8;
typedef __attribute__((ext_vector_type(4))) float f32x4;

constexpr int N   = 50000;
constexpr int E   = 1600000;
constexpr int C   = 128;             // channels (H * 32)
constexpr int H   = 4;               // heads
constexpr int NB  = 782;             // dst buckets of 64 nodes (782*64 >= 50000)
constexpr int CAP = 2560;            // LDS staging capacity per bucket in kfill2
constexpr int NCH = 256;             // chunks (bin-count blocks)
constexpr int CHUNK = E / NCH;       // 6250 edges per chunk (exact)
constexpr int GEMM_BLOCKS = 782;     // 782*64 >= 50000 nodes
constexpr float NEG  = 0.2f;
constexpr float SEPS = 1e-16f;
constexpr float LEPS = 1e-5f;

__device__ __forceinline__ float lo16(u32 v) { return __uint_as_float(v << 16); }
__device__ __forceinline__ float hi16(u32 v) { return __uint_as_float(v & 0xFFFF0000u); }
__device__ __forceinline__ u16 bfbits(float f) {
    __hip_bfloat16 h = __float2bfloat16(f);
    return *reinterpret_cast<u16*>(&h);
}

// F1: fused independent front-end (unchanged from R5 — control).
__global__ __launch_bounds__(256) void f1_gemm_count(
    const float* __restrict__ x, const float* __restrict__ W,
    const float* __restrict__ att_s, const float* __restrict__ att_d,
    const int* __restrict__ ei,
    u16* __restrict__ hb, float* __restrict__ as_, float* __restrict__ ad_,
    u32* __restrict__ gcnt)
{
    constexpr int LDX = 136;                  // row stride in bf16 elems (128+8)
    union Smem {
        struct { u16 xhi[64 * LDX]; u16 xlo[64 * LDX]; } g;   // 34816 B
        u32 lcnt[NB];                                          // 3128 B
    };
    __shared__ Smem sm;
    const int t = threadIdx.x;

    if (blockIdx.x >= GEMM_BLOCKS) {
        // ---- bin count branch ----
        const int c = blockIdx.x - GEMM_BLOCKS;
        const int base = c * CHUNK;
        for (int i = t; i < NB; i += 256) sm.lcnt[i] = 0;
        __syncthreads();
        for (int i = t; i < CHUNK; i += 256)
            atomicAdd(&sm.lcnt[((u32)ei[E + base + i]) >> 6], 1u);
        __syncthreads();
        for (int i = t; i < NB; i += 256) gcnt[i * NCH + c] = sm.lcnt[i];
        return;
    }

    // ---- GEMM branch ----
    const int m0 = blockIdx.x * 64;

#pragma unroll
    for (int it = 0; it < 8; ++it) {
        const int idx = it * 1024 + t * 4;
        const int r = idx >> 7, cc = idx & 127;
        const int gr = min(m0 + r, N - 1);
        const float4 v = *(const float4*)(x + (size_t)gr * 128 + cc);
        ushort4 sh, sl;
        {
            __hip_bfloat16 h0 = __float2bfloat16(v.x);
            __hip_bfloat16 h1 = __float2bfloat16(v.y);
            __hip_bfloat16 h2 = __float2bfloat16(v.z);
            __hip_bfloat16 h3 = __float2bfloat16(v.w);
            sh.x = *(u16*)&h0; sh.y = *(u16*)&h1; sh.z = *(u16*)&h2; sh.w = *(u16*)&h3;
            sl.x = bfbits(v.x - __bfloat162float(h0));
            sl.y = bfbits(v.y - __bfloat162float(h1));
            sl.z = bfbits(v.z - __bfloat162float(h2));
            sl.w = bfbits(v.w - __bfloat162float(h3));
        }
        *(ushort4*)(sm.g.xhi + r * LDX + cc) = sh;
        *(ushort4*)(sm.g.xlo + r * LDX + cc) = sl;
    }
    __syncthreads();

    const int lane = t & 63;
    const int w    = t >> 6;
    const int arow = w * 16 + (lane & 15);
    const int akg  = lane >> 4;
    const int bcol = lane & 15;
    const int aq   = lane >> 4;

    bf16x8 Ah[4], Al[4];
#pragma unroll
    for (int ks = 0; ks < 4; ++ks) {
        Ah[ks] = *(const bf16x8*)(sm.g.xhi + arow * LDX + ks * 32 + akg * 8);
        Al[ks] = *(const bf16x8*)(sm.g.xlo + arow * LDX + ks * 32 + akg * 8);
    }

    f32x4 acc[8];
#pragma unroll
    for (int nt = 0; nt < 8; ++nt) acc[nt] = f32x4{0.f, 0.f, 0.f, 0.f};

#pragma unroll
    for (int nt = 0; nt < 8; ++nt) {
        const int ch = nt * 16 + bcol;
#pragma unroll
        for (int ks = 0; ks < 4; ++ks) {
            const int kk = ks * 32 + akg * 8;
            bf16x8 Bh, Bl;
#pragma unroll
            for (int j = 0; j < 8; ++j) {
                const float wv = W[(size_t)(kk + j) * 128 + ch];
                const __hip_bfloat16 hh = __float2bfloat16(wv);
                Bh[j] = *(const short*)&hh;
                const __hip_bfloat16 hl = __float2bfloat16(wv - __bfloat162float(hh));
                Bl[j] = *(const short*)&hl;
            }
            acc[nt] = __builtin_amdgcn_mfma_f32_16x16x32_bf16(Ah[ks], Bh, acc[nt], 0, 0, 0);
            acc[nt] = __builtin_amdgcn_mfma_f32_16x16x32_bf16(Al[ks], Bh, acc[nt], 0, 0, 0);
            acc[nt] = __builtin_amdgcn_mfma_f32_16x16x32_bf16(Ah[ks], Bl, acc[nt], 0, 0, 0);
        }
    }

    // hb store: C/D layout col=lane&15, row=(lane>>4)*4+reg  [m89/m91]
#pragma unroll
    for (int nt = 0; nt < 8; ++nt) {
        const int ch = nt * 16 + bcol;
#pragma unroll
        for (int r = 0; r < 4; ++r) {
            const int node = m0 + w * 16 + aq * 4 + r;
            if (node < N) hb[(size_t)node * 128 + ch] = bfbits(acc[nt][r]);
        }
    }

    float ps[4][4], pd[4][4];
#pragma unroll
    for (int h = 0; h < 4; ++h) {
        const float a0 = att_s[32 * h + bcol], a1 = att_s[32 * h + 16 + bcol];
        const float d0 = att_d[32 * h + bcol], d1 = att_d[32 * h + 16 + bcol];
#pragma unroll
        for (int r = 0; r < 4; ++r) {
            ps[h][r] = acc[2 * h][r] * a0 + acc[2 * h + 1][r] * a1;
            pd[h][r] = acc[2 * h][r] * d0 + acc[2 * h + 1][r] * d1;
        }
    }
#pragma unroll
    for (int off = 1; off < 16; off <<= 1) {
#pragma unroll
        for (int h = 0; h < 4; ++h)
#pragma unroll
            for (int r = 0; r < 4; ++r) {
                ps[h][r] += __shfl_xor(ps[h][r], off, 64);
                pd[h][r] += __shfl_xor(pd[h][r], off, 64);
            }
    }
    if (bcol == 0) {
#pragma unroll
        for (int r = 0; r < 4; ++r) {
            const int node = m0 + w * 16 + aq * 4 + r;
            if (node < N) {
#pragma unroll
                for (int h = 0; h < 4; ++h) {
                    as_[node * H + h] = ps[h][r];
                    ad_[node * H + h] = pd[h][r];
                }
            }
        }
    }
}

// S2A (unchanged — control).
__global__ __launch_bounds__(256) void s2a_scan(
    const u32* __restrict__ gcnt, u32* __restrict__ gbase, u32* __restrict__ tot)
{
    __shared__ u32 wsum[4];
    const int b = blockIdx.x, t = threadIdx.x, lane = t & 63, w = t >> 6;
    const u32 v = gcnt[b * NCH + t];
    u32 incl = v;
#pragma unroll
    for (int off = 1; off < 64; off <<= 1) {
        u32 u = __shfl_up(incl, off, 64);
        if (lane >= off) incl += u;
    }
    if (lane == 63) wsum[w] = incl;
    __syncthreads();
    u32 wpre = 0;
#pragma unroll
    for (int i = 0; i < 4; ++i) if (i < w) wpre += wsum[i];
    gbase[b * NCH + t] = wpre + incl - v;
    if (t == 255) tot[b] = wpre + incl;
}

// KBINB (unchanged — control).
__global__ __launch_bounds__(256) void kbinB(
    const int* __restrict__ ei, const u32* __restrict__ gbase,
    const u32* __restrict__ tot, u32* __restrict__ pairs)
{
    __shared__ u32 sl[NB];
    __shared__ u32 lfill[NB];
    __shared__ u32 wsum[4];
    const int t = threadIdx.x, lane = t & 63, w = t >> 6;
    const int c = blockIdx.x;

    u32 carry = 0;
    for (int q = 0; q < 4; ++q) {
        const int idx = q * 256 + t;
        const u32 v = (idx < NB) ? tot[idx] : 0u;
        u32 incl = v;
#pragma unroll
        for (int off = 1; off < 64; off <<= 1) {
            u32 u = __shfl_up(incl, off, 64);
            if (lane >= off) incl += u;
        }
        if (lane == 63) wsum[w] = incl;
        __syncthreads();
        u32 wpre = 0, wtot = 0;
#pragma unroll
        for (int i = 0; i < 4; ++i) { const u32 s = wsum[i]; wtot += s; if (i < w) wpre += s; }
        if (idx < NB) sl[idx] = carry + wpre + (incl - v) + gbase[(size_t)idx * NCH + c];
        carry += wtot;
        __syncthreads();
    }
    for (int i = t; i < NB; i += 256) lfill[i] = 0u;
    __syncthreads();

    const int base = c * CHUNK;
    for (int i = t; i < CHUNK; i += 256) {
        const u32 src = (u32)ei[base + i];
        const u32 dst = (u32)ei[E + base + i];
        const u32 b = dst >> 6;
        const u32 pos = atomicAdd(&lfill[b], 1u);
        pairs[sl[b] + pos] = src | ((dst & 63u) << 16);
    }
}

// KFILL2 (unchanged — control).
__global__ __launch_bounds__(256) void kfill2(
    const u32* __restrict__ pairs, const u32* __restrict__ tot,
    int* __restrict__ row_ptr, u16* __restrict__ col)
{
    __shared__ u32 spr[CAP];
    __shared__ u16 scol[CAP];
    __shared__ int jcnt[64], joff[64], jcur[64];
    __shared__ u32 rsum[4];
    const int b = blockIdx.x, t = threadIdx.x;
    const int lane = t & 63, w = t >> 6;

    u32 part = 0;
    for (int i = t; i < b; i += 256) part += tot[i];
#pragma unroll
    for (int off = 32; off; off >>= 1) part += __shfl_xor(part, off, 64);
    if (lane == 0) rsum[w] = part;
    if (t < 64) jcnt[t] = 0;
    __syncthreads();
    const int base = (int)(rsum[0] + rsum[1] + rsum[2] + rsum[3]);
    const int cntb = (int)tot[b];

    const u32* pr = pairs + base;
    for (int i = t; i < cntb; i += 256) spr[i] = pr[i];
    __syncthreads();
    for (int i = t; i < cntb; i += 256) atomicAdd(&jcnt[spr[i] >> 16], 1);
    __syncthreads();
    if (t < 64) {
        int v = jcnt[t], incl = v;
#pragma unroll
        for (int off = 1; off < 64; off <<= 1) {
            int u = __shfl_up(incl, off, 64);
            if (t >= off) incl += u;
        }
        joff[t] = incl - v;
        const int n = b * 64 + t;
        if (n < N) row_ptr[n] = base + joff[t];
        jcur[t] = 0;
    }
    __syncthreads();
    for (int i = t; i < cntb; i += 256) {
        const u32 p = spr[i];
        const int j = p >> 16;
        const int pos = atomicAdd(&jcur[j], 1);
        scol[joff[j] + pos] = (u16)(p & 0xFFFFu);
    }
    __syncthreads();
    for (int i = t; i < cntb; i += 256) col[base + i] = scol[i];
    if (b == 0 && t == 0) row_ptr[N] = E;
}

// KD v5: 2-tile-deep hb gather pipeline (32 loads in flight per wave).
// Tile t+1's 16 loads are issued BEFORE consuming tile t's (two named
// register sets, 2x-unrolled loop -> all static indexing). col pipelined
// 3 deep, as_ 2 deep, as before. Everything else identical to v4.
__global__ __launch_bounds__(256) void kd_agg_ln(
    const int* __restrict__ row_ptr, const u16* __restrict__ col,
    const u32* __restrict__ hb, const float* __restrict__ as_,
    const float* __restrict__ ad_,
    const float* __restrict__ bias, const float* __restrict__ gamma,
    const float* __restrict__ beta, float* __restrict__ out)
{
    __shared__ float wlds[4][64];
    const int tid  = threadIdx.x;
    const int lane = tid & 63;
    const int wv   = __builtin_amdgcn_readfirstlane(tid >> 6);
    const int n    = __builtin_amdgcn_readfirstlane((int)blockIdx.x * 4 + (tid >> 6));
    if (n >= N) return;

    const int head  = lane >> 4;
    const int eoff  = lane & 15;
    const int wbase = head << 4;
    float* __restrict__ wrow = wlds[wv];

    const float adn = ad_[n * H + head];
    const float asn = as_[n * H + head];

    float ls = asn + adn;
    ls = fmaxf(ls, NEG * ls);
    const float wself = __expf(ls);
    float den = (eoff == 0) ? wself : 0.f;
    const u32 hvs = hb[n * 64 + lane];
    float num0 = wself * lo16(hvs);
    float num1 = wself * hi16(hvs);

    const int k0  = row_ptr[n];
    const int deg = row_ptr[n + 1] - k0;
    const int ntiles = (deg + 15) >> 4;

    const int cnt0 = deg < 16 ? deg : 16;
    const int cnt1 = (deg - 16) < 16 ? (deg - 16) : 16;
    int colv_cur = (eoff < cnt0) ? (int)col[k0 + eoff]      : 0;
    int colv_nxt = (eoff < cnt1) ? (int)col[k0 + 16 + eoff] : 0;
    float a_cur  = as_[colv_cur * H + head];
    int cntc = cnt0, cntn = cnt1;

    // two in-flight register sets
    u32 vA0, vA1, vA2, vA3, vA4, vA5, vA6, vA7,
        vA8, vA9, vA10, vA11, vA12, vA13, vA14, vA15;
    u32 vB0, vB1, vB2, vB3, vB4, vB5, vB6, vB7,
        vB8, vB9, vB10, vB11, vB12, vB13, vB14, vB15;

#define ISSUE16(P, colc)                                                        \
    P##0  = hb[((size_t)(u32)__builtin_amdgcn_readlane(colc, 0)  << 6) + lane]; \
    P##1  = hb[((size_t)(u32)__builtin_amdgcn_readlane(colc, 1)  << 6) + lane]; \
    P##2  = hb[((size_t)(u32)__builtin_amdgcn_readlane(colc, 2)  << 6) + lane]; \
    P##3  = hb[((size_t)(u32)__builtin_amdgcn_readlane(colc, 3)  << 6) + lane]; \
    P##4  = hb[((size_t)(u32)__builtin_amdgcn_readlane(colc, 4)  << 6) + lane]; \
    P##5  = hb[((size_t)(u32)__builtin_amdgcn_readlane(colc, 5)  << 6) + lane]; \
    P##6  = hb[((size_t)(u32)__builtin_amdgcn_readlane(colc, 6)  << 6) + lane]; \
    P##7  = hb[((size_t)(u32)__builtin_amdgcn_readlane(colc, 7)  << 6) + lane]; \
    P##8  = hb[((size_t)(u32)__builtin_amdgcn_readlane(colc, 8)  << 6) + lane]; \
    P##9  = hb[((size_t)(u32)__builtin_amdgcn_readlane(colc, 9)  << 6) + lane]; \
    P##10 = hb[((size_t)(u32)__builtin_amdgcn_readlane(colc, 10) << 6) + lane]; \
    P##11 = hb[((size_t)(u32)__builtin_amdgcn_readlane(colc, 11) << 6) + lane]; \
    P##12 = hb[((size_t)(u32)__builtin_amdgcn_readlane(colc, 12) << 6) + lane]; \
    P##13 = hb[((size_t)(u32)__builtin_amdgcn_readlane(colc, 13) << 6) + lane]; \
    P##14 = hb[((size_t)(u32)__builtin_amdgcn_readlane(colc, 14) << 6) + lane]; \
    P##15 = hb[((size_t)(u32)__builtin_amdgcn_readlane(colc, 15) << 6) + lane];

#define CONSUME(P)                                                              \
    {                                                                           \
        const float4 wa = *(const float4*)(wrow + wbase + 0);                   \
        num0 = fmaf(wa.x, lo16(P##0), num0);  num1 = fmaf(wa.x, hi16(P##0), num1); \
        num0 = fmaf(wa.y, lo16(P##1), num0);  num1 = fmaf(wa.y, hi16(P##1), num1); \
        num0 = fmaf(wa.z, lo16(P##2), num0);  num1 = fmaf(wa.z, hi16(P##2), num1); \
        num0 = fmaf(wa.w, lo16(P##3), num0);  num1 = fmaf(wa.w, hi16(P##3), num1); \
        const float4 wb = *(const float4*)(wrow + wbase + 4);                   \
        num0 = fmaf(wb.x, lo16(P##4), num0);  num1 = fmaf(wb.x, hi16(P##4), num1); \
        num0 = fmaf(wb.y, lo16(P##5), num0);  num1 = fmaf(wb.y, hi16(P##5), num1); \
        num0 = fmaf(wb.z, lo16(P##6), num0);  num1 = fmaf(wb.z, hi16(P##6), num1); \
        num0 = fmaf(wb.w, lo16(P##7), num0);  num1 = fmaf(wb.w, hi16(P##7), num1); \
        const float4 wc = *(const float4*)(wrow + wbase + 8);                   \
        num0 = fmaf(wc.x, lo16(P##8), num0);  num1 = fmaf(wc.x, hi16(P##8), num1); \
        num0 = fmaf(wc.y, lo16(P##9), num0);  num1 = fmaf(wc.y, hi16(P##9), num1); \
        num0 = fmaf(wc.z, lo16(P##10), num0); num1 = fmaf(wc.z, hi16(P##10), num1); \
        num0 = fmaf(wc.w, lo16(P##11), num0); num1 = fmaf(wc.w, hi16(P##11), num1); \
        const float4 wd = *(const float4*)(wrow + wbase + 12);                  \
        num0 = fmaf(wd.x, lo16(P##12), num0); num1 = fmaf(wd.x, hi16(P##12), num1); \
        num0 = fmaf(wd.y, lo16(P##13), num0); num1 = fmaf(wd.y, hi16(P##13), num1); \
        num0 = fmaf(wd.z, lo16(P##14), num0); num1 = fmaf(wd.z, hi16(P##14), num1); \
        num0 = fmaf(wd.w, lo16(P##15), num0); num1 = fmaf(wd.w, hi16(P##15), num1); \
    }

// One pipeline step: weights for tile t, issue loads for t+1 into VN,
// prefetch col(t+2)/as_(t+1), consume VC (tile t), rotate state.
#define STEP(VC, VN)                                                            \
    {                                                                           \
        const int rem2 = deg - 16 * (t + 2);                                    \
        const int cnt2 = rem2 < 16 ? rem2 : 16;                                 \
        const int cf_raw = (int)col[k + 32 + eoff];                             \
        const int colv_f = (eoff < cnt2) ? cf_raw : 0;                          \
        float le = a_cur + adn;                                                 \
        le = fmaxf(le, NEG * le);                                               \
        const float w = (eoff < cntc) ? __expf(le) : 0.f;                       \
        den += w;                                                               \
        wrow[lane] = w;                                                         \
        ISSUE16(VN, colv_nxt)                                                   \
        __builtin_amdgcn_sched_barrier(0);                                      \
        const float a_n = as_[colv_nxt * H + head];                             \
        __builtin_amdgcn_sched_barrier(0);                                      \
        CONSUME(VC)                                                             \
        colv_cur = colv_nxt; colv_nxt = colv_f;                                 \
        a_cur = a_n;                                                            \
        cntc = cntn; cntn = cnt2;                                               \
        ++t; k += 16;                                                           \
    }

    int t = 0;
    int k = k0;
    // prologue: tile 0's loads in flight in set A
    ISSUE16(vA, colv_cur)
    __builtin_amdgcn_sched_barrier(0);

    while (t + 2 <= ntiles) {
        STEP(vA, vB)
        STEP(vB, vA)
    }
    if (t < ntiles) {
        STEP(vA, vB)       // final tile; its issue targets masked zeros (row 0)
    }

#undef STEP
#undef CONSUME
#undef ISSUE16

#pragma unroll
    for (int off = 1; off < 16; off <<= 1) den += __shfl_xor(den, off, 64);

    const int c0 = lane * 2;
    const float inv_den = 1.f / (den + SEPS);
    const float2 bi = *(const float2*)(bias + c0);
    float v0 = num0 * inv_den + bi.x;
    float v1 = num1 * inv_den + bi.y;

    float sum = v0 + v1;
#pragma unroll
    for (int off = 32; off; off >>= 1) sum += __shfl_xor(sum, off, 64);
    const float mu = sum * (1.0f / C);
    const float d0 = v0 - mu, d1 = v1 - mu;
    float sq = d0 * d0 + d1 * d1;
#pragma unroll
    for (int off = 32; off; off >>= 1) sq += __shfl_xor(sq, off, 64);
    const float inv = rsqrtf(sq * (1.0f / C) + LEPS);
    const float2 ga = *(const float2*)(gamma + c0);
    const float2 be = *(const float2*)(beta  + c0);
    float y0 = d0 * inv * ga.x + be.x;
    float y1 = d1 * inv * ga.y + be.y;
    y0 = y0 > 0.f ? y0 : __expf(y0) - 1.f;
    y1 = y1 > 0.f ? y1 : __expf(y1) - 1.f;
    float2 o; o.x = y0; o.y = y1;
    *(float2*)(out + (size_t)n * C + c0) = o;
}

extern "C" void kernel_launch(void* const* d_in, const int* in_sizes, int n_in,
                              void* d_out, int out_size, void* d_ws, size_t ws_size,
                              hipStream_t stream)
{
    const float* x     = (const float*)d_in[0];
    const int*   ei    = (const int*)  d_in[1];
    const float* W     = (const float*)d_in[2];
    const float* att_s = (const float*)d_in[3];
    const float* att_d = (const float*)d_in[4];
    const float* bias  = (const float*)d_in[5];
    const float* gamma = (const float*)d_in[6];
    const float* beta  = (const float*)d_in[7];
    float* out = (float*)d_out;

    // ws (~25.8 MB): hb bf16[N*C] | as_ | ad_ | pairs u32[E] | col u16[E+64]
    //              | row_ptr int[N+1] | gcnt u32[NB*256] | gbase u32[NB*256] | tot u32[NB]
    char* p = (char*)d_ws;
    bf16*  hb      = (bf16*)p;   p += (size_t)N * C * sizeof(bf16);
    float* as_     = (float*)p;  p += (size_t)N * H * sizeof(float);
    float* ad_     = (float*)p;  p += (size_t)N * H * sizeof(float);
    u32*   pairs   = (u32*)p;    p += (size_t)E * sizeof(u32);
    u16*   col     = (u16*)p;    p += ((size_t)(E + 64) * sizeof(u16) + 15) & ~(size_t)15;
    int*   row_ptr = (int*)p;    p += ((size_t)(N + 1) * sizeof(int) + 15) & ~(size_t)15;
    u32*   gcnt    = (u32*)p;    p += (size_t)NB * NCH * sizeof(u32);
    u32*   gbase   = (u32*)p;    p += (size_t)NB * NCH * sizeof(u32);
    u32*   tot     = (u32*)p;

    f1_gemm_count<<<GEMM_BLOCKS + NCH, 256, 0, stream>>>(
        x, W, att_s, att_d, ei, (u16*)hb, as_, ad_, gcnt);
    s2a_scan<<<NB, 256, 0, stream>>>(gcnt, gbase, tot);
    kbinB<<<NCH, 256, 0, stream>>>(ei, gbase, tot, pairs);
    kfill2<<<NB, 256, 0, stream>>>(pairs, tot, row_ptr, col);
    kd_agg_ln<<<(N * 64) / 256, 256, 0, stream>>>(
        row_ptr, col, (const u32*)hb, as_, ad_, bias, gamma, beta, out);
}

// Round 7
// 209.372 us; speedup vs baseline: 1.0505x; 1.0505x over previous
//
#include <hip/hip_runtime.h>
#include <hip/hip_bf16.h>

typedef __hip_bfloat16 bf16;
typedef unsigned int u32;
typedef unsigned short u16;
typedef __attribute__((ext_vector_type(8))) short bf16x8;
typedef __attribute__((ext_vector_type(4))) float f32x4;

constexpr int N   = 50000;
constexpr int E   = 1600000;
constexpr int C   = 128;             // channels (H * 32)
constexpr int H   = 4;               // heads
constexpr int NB  = 782;             // dst buckets of 64 nodes (782*64 >= 50000)
constexpr int CAP = 2560;            // LDS staging capacity per bucket in kfill2
constexpr int NCH = 256;             // chunks (bin-count blocks)
constexpr int CHUNK = E / NCH;       // 6250 edges per chunk (exact)
constexpr int GEMM_BLOCKS = 782;     // 782*64 >= 50000 nodes
constexpr float NEG  = 0.2f;
constexpr float SEPS = 1e-16f;
constexpr float LEPS = 1e-5f;

__device__ __forceinline__ float lo16(u32 v) { return __uint_as_float(v << 16); }
__device__ __forceinline__ float hi16(u32 v) { return __uint_as_float(v & 0xFFFF0000u); }
__device__ __forceinline__ u16 bfbits(float f) {
    __hip_bfloat16 h = __float2bfloat16(f);
    return *reinterpret_cast<u16*>(&h);
}

// F1: fused independent front-end (unchanged — control).
__global__ __launch_bounds__(256) void f1_gemm_count(
    const float* __restrict__ x, const float* __restrict__ W,
    const float* __restrict__ att_s, const float* __restrict__ att_d,
    const int* __restrict__ ei,
    u16* __restrict__ hb, float* __restrict__ as_, float* __restrict__ ad_,
    u32* __restrict__ gcnt)
{
    constexpr int LDX = 136;                  // row stride in bf16 elems (128+8)
    union Smem {
        struct { u16 xhi[64 * LDX]; u16 xlo[64 * LDX]; } g;   // 34816 B
        u32 lcnt[NB];                                          // 3128 B
    };
    __shared__ Smem sm;
    const int t = threadIdx.x;

    if (blockIdx.x >= GEMM_BLOCKS) {
        // ---- bin count branch ----
        const int c = blockIdx.x - GEMM_BLOCKS;
        const int base = c * CHUNK;
        for (int i = t; i < NB; i += 256) sm.lcnt[i] = 0;
        __syncthreads();
        for (int i = t; i < CHUNK; i += 256)
            atomicAdd(&sm.lcnt[((u32)ei[E + base + i]) >> 6], 1u);
        __syncthreads();
        for (int i = t; i < NB; i += 256) gcnt[i * NCH + c] = sm.lcnt[i];
        return;
    }

    // ---- GEMM branch ----
    const int m0 = blockIdx.x * 64;

#pragma unroll
    for (int it = 0; it < 8; ++it) {
        const int idx = it * 1024 + t * 4;
        const int r = idx >> 7, cc = idx & 127;
        const int gr = min(m0 + r, N - 1);
        const float4 v = *(const float4*)(x + (size_t)gr * 128 + cc);
        ushort4 sh, sl;
        {
            __hip_bfloat16 h0 = __float2bfloat16(v.x);
            __hip_bfloat16 h1 = __float2bfloat16(v.y);
            __hip_bfloat16 h2 = __float2bfloat16(v.z);
            __hip_bfloat16 h3 = __float2bfloat16(v.w);
            sh.x = *(u16*)&h0; sh.y = *(u16*)&h1; sh.z = *(u16*)&h2; sh.w = *(u16*)&h3;
            sl.x = bfbits(v.x - __bfloat162float(h0));
            sl.y = bfbits(v.y - __bfloat162float(h1));
            sl.z = bfbits(v.z - __bfloat162float(h2));
            sl.w = bfbits(v.w - __bfloat162float(h3));
        }
        *(ushort4*)(sm.g.xhi + r * LDX + cc) = sh;
        *(ushort4*)(sm.g.xlo + r * LDX + cc) = sl;
    }
    __syncthreads();

    const int lane = t & 63;
    const int w    = t >> 6;
    const int arow = w * 16 + (lane & 15);
    const int akg  = lane >> 4;
    const int bcol = lane & 15;
    const int aq   = lane >> 4;

    bf16x8 Ah[4], Al[4];
#pragma unroll
    for (int ks = 0; ks < 4; ++ks) {
        Ah[ks] = *(const bf16x8*)(sm.g.xhi + arow * LDX + ks * 32 + akg * 8);
        Al[ks] = *(const bf16x8*)(sm.g.xlo + arow * LDX + ks * 32 + akg * 8);
    }

    f32x4 acc[8];
#pragma unroll
    for (int nt = 0; nt < 8; ++nt) acc[nt] = f32x4{0.f, 0.f, 0.f, 0.f};

#pragma unroll
    for (int nt = 0; nt < 8; ++nt) {
        const int ch = nt * 16 + bcol;
#pragma unroll
        for (int ks = 0; ks < 4; ++ks) {
            const int kk = ks * 32 + akg * 8;
            bf16x8 Bh, Bl;
#pragma unroll
            for (int j = 0; j < 8; ++j) {
                const float wv = W[(size_t)(kk + j) * 128 + ch];
                const __hip_bfloat16 hh = __float2bfloat16(wv);
                Bh[j] = *(const short*)&hh;
                const __hip_bfloat16 hl = __float2bfloat16(wv - __bfloat162float(hh));
                Bl[j] = *(const short*)&hl;
            }
            acc[nt] = __builtin_amdgcn_mfma_f32_16x16x32_bf16(Ah[ks], Bh, acc[nt], 0, 0, 0);
            acc[nt] = __builtin_amdgcn_mfma_f32_16x16x32_bf16(Al[ks], Bh, acc[nt], 0, 0, 0);
            acc[nt] = __builtin_amdgcn_mfma_f32_16x16x32_bf16(Ah[ks], Bl, acc[nt], 0, 0, 0);
        }
    }

    // hb store: C/D layout col=lane&15, row=(lane>>4)*4+reg  [m89/m91]
#pragma unroll
    for (int nt = 0; nt < 8; ++nt) {
        const int ch = nt * 16 + bcol;
#pragma unroll
        for (int r = 0; r < 4; ++r) {
            const int node = m0 + w * 16 + aq * 4 + r;
            if (node < N) hb[(size_t)node * 128 + ch] = bfbits(acc[nt][r]);
        }
    }

    float ps[4][4], pd[4][4];
#pragma unroll
    for (int h = 0; h < 4; ++h) {
        const float a0 = att_s[32 * h + bcol], a1 = att_s[32 * h + 16 + bcol];
        const float d0 = att_d[32 * h + bcol], d1 = att_d[32 * h + 16 + bcol];
#pragma unroll
        for (int r = 0; r < 4; ++r) {
            ps[h][r] = acc[2 * h][r] * a0 + acc[2 * h + 1][r] * a1;
            pd[h][r] = acc[2 * h][r] * d0 + acc[2 * h + 1][r] * d1;
        }
    }
#pragma unroll
    for (int off = 1; off < 16; off <<= 1) {
#pragma unroll
        for (int h = 0; h < 4; ++h)
#pragma unroll
            for (int r = 0; r < 4; ++r) {
                ps[h][r] += __shfl_xor(ps[h][r], off, 64);
                pd[h][r] += __shfl_xor(pd[h][r], off, 64);
            }
    }
    if (bcol == 0) {
#pragma unroll
        for (int r = 0; r < 4; ++r) {
            const int node = m0 + w * 16 + aq * 4 + r;
            if (node < N) {
#pragma unroll
                for (int h = 0; h < 4; ++h) {
                    as_[node * H + h] = ps[h][r];
                    ad_[node * H + h] = pd[h][r];
                }
            }
        }
    }
}

// S2A (unchanged — control).
__global__ __launch_bounds__(256) void s2a_scan(
    const u32* __restrict__ gcnt, u32* __restrict__ gbase, u32* __restrict__ tot)
{
    __shared__ u32 wsum[4];
    const int b = blockIdx.x, t = threadIdx.x, lane = t & 63, w = t >> 6;
    const u32 v = gcnt[b * NCH + t];
    u32 incl = v;
#pragma unroll
    for (int off = 1; off < 64; off <<= 1) {
        u32 u = __shfl_up(incl, off, 64);
        if (lane >= off) incl += u;
    }
    if (lane == 63) wsum[w] = incl;
    __syncthreads();
    u32 wpre = 0;
#pragma unroll
    for (int i = 0; i < 4; ++i) if (i < w) wpre += wsum[i];
    gbase[b * NCH + t] = wpre + incl - v;
    if (t == 255) tot[b] = wpre + incl;
}

// KBINB (unchanged — control).
__global__ __launch_bounds__(256) void kbinB(
    const int* __restrict__ ei, const u32* __restrict__ gbase,
    const u32* __restrict__ tot, u32* __restrict__ pairs)
{
    __shared__ u32 sl[NB];
    __shared__ u32 lfill[NB];
    __shared__ u32 wsum[4];
    const int t = threadIdx.x, lane = t & 63, w = t >> 6;
    const int c = blockIdx.x;

    u32 carry = 0;
    for (int q = 0; q < 4; ++q) {
        const int idx = q * 256 + t;
        const u32 v = (idx < NB) ? tot[idx] : 0u;
        u32 incl = v;
#pragma unroll
        for (int off = 1; off < 64; off <<= 1) {
            u32 u = __shfl_up(incl, off, 64);
            if (lane >= off) incl += u;
        }
        if (lane == 63) wsum[w] = incl;
        __syncthreads();
        u32 wpre = 0, wtot = 0;
#pragma unroll
        for (int i = 0; i < 4; ++i) { const u32 s = wsum[i]; wtot += s; if (i < w) wpre += s; }
        if (idx < NB) sl[idx] = carry + wpre + (incl - v) + gbase[(size_t)idx * NCH + c];
        carry += wtot;
        __syncthreads();
    }
    for (int i = t; i < NB; i += 256) lfill[i] = 0u;
    __syncthreads();

    const int base = c * CHUNK;
    for (int i = t; i < CHUNK; i += 256) {
        const u32 src = (u32)ei[base + i];
        const u32 dst = (u32)ei[E + base + i];
        const u32 b = dst >> 6;
        const u32 pos = atomicAdd(&lfill[b], 1u);
        pairs[sl[b] + pos] = src | ((dst & 63u) << 16);
    }
}

// KFILL2 (unchanged — control).
__global__ __launch_bounds__(256) void kfill2(
    const u32* __restrict__ pairs, const u32* __restrict__ tot,
    int* __restrict__ row_ptr, u16* __restrict__ col)
{
    __shared__ u32 spr[CAP];
    __shared__ u16 scol[CAP];
    __shared__ int jcnt[64], joff[64], jcur[64];
    __shared__ u32 rsum[4];
    const int b = blockIdx.x, t = threadIdx.x;
    const int lane = t & 63, w = t >> 6;

    u32 part = 0;
    for (int i = t; i < b; i += 256) part += tot[i];
#pragma unroll
    for (int off = 32; off; off >>= 1) part += __shfl_xor(part, off, 64);
    if (lane == 0) rsum[w] = part;
    if (t < 64) jcnt[t] = 0;
    __syncthreads();
    const int base = (int)(rsum[0] + rsum[1] + rsum[2] + rsum[3]);
    const int cntb = (int)tot[b];

    const u32* pr = pairs + base;
    for (int i = t; i < cntb; i += 256) spr[i] = pr[i];
    __syncthreads();
    for (int i = t; i < cntb; i += 256) atomicAdd(&jcnt[spr[i] >> 16], 1);
    __syncthreads();
    if (t < 64) {
        int v = jcnt[t], incl = v;
#pragma unroll
        for (int off = 1; off < 64; off <<= 1) {
            int u = __shfl_up(incl, off, 64);
            if (t >= off) incl += u;
        }
        joff[t] = incl - v;
        const int n = b * 64 + t;
        if (n < N) row_ptr[n] = base + joff[t];
        jcur[t] = 0;
    }
    __syncthreads();
    for (int i = t; i < cntb; i += 256) {
        const u32 p = spr[i];
        const int j = p >> 16;
        const int pos = atomicAdd(&jcur[j], 1);
        scol[joff[j] + pos] = (u16)(p & 0xFFFFu);
    }
    __syncthreads();
    for (int i = t; i < cntb; i += 256) col[base + i] = scol[i];
    if (b == 0 && t == 0) row_ptr[N] = E;
}

// KD v4 (reverted from v5 — the R3-R5 55 µs version), plus an n0 offset so it
// can run as two half-dispatches (~28 µs each). Numerically identical; the
// split exists to let hidden kernels surface in the rocprof top-5 table.
__global__ __launch_bounds__(256) void kd_agg_ln(
    const int* __restrict__ row_ptr, const u16* __restrict__ col,
    const u32* __restrict__ hb, const float* __restrict__ as_,
    const float* __restrict__ ad_,
    const float* __restrict__ bias, const float* __restrict__ gamma,
    const float* __restrict__ beta, float* __restrict__ out, int n0)
{
    __shared__ float wlds[4][64];
    const int tid  = threadIdx.x;
    const int lane = tid & 63;
    const int wv   = __builtin_amdgcn_readfirstlane(tid >> 6);
    const int n    = __builtin_amdgcn_readfirstlane(n0 + (int)blockIdx.x * 4 + (tid >> 6));
    if (n >= N) return;

    const int head  = lane >> 4;
    const int eoff  = lane & 15;
    const int wbase = head << 4;
    float* __restrict__ wrow = wlds[wv];

    const float adn = ad_[n * H + head];
    const float asn = as_[n * H + head];

    float ls = asn + adn;
    ls = fmaxf(ls, NEG * ls);
    const float wself = __expf(ls);
    float den = (eoff == 0) ? wself : 0.f;
    const u32 hvs = hb[n * 64 + lane];
    float num0 = wself * lo16(hvs);
    float num1 = wself * hi16(hvs);

    const int k0  = row_ptr[n];
    const int deg = row_ptr[n + 1] - k0;
    const int ntiles = (deg + 15) >> 4;

    const int cnt0 = deg < 16 ? deg : 16;
    const int cnt1 = (deg - 16) < 16 ? (deg - 16) : 16;
    int colv_cur = (eoff < cnt0) ? (int)col[k0 + eoff]      : 0;
    int colv_nxt = (eoff < cnt1) ? (int)col[k0 + 16 + eoff] : 0;
    float a_cur  = as_[colv_cur * H + head];
    int cntc = cnt0, cntn = cnt1;

    int k = k0;
    for (int t = 0; t < ntiles; ++t, k += 16) {
        const int rem2 = deg - 16 * (t + 2);
        const int cnt2 = rem2 < 16 ? rem2 : 16;
        const int cf_raw = (int)col[k + 32 + eoff];
        const int colv_f = (eoff < cnt2) ? cf_raw : 0;

        float le = a_cur + adn;
        le = fmaxf(le, NEG * le);
        const float w = (eoff < cntc) ? __expf(le) : 0.f;
        den += w;
        wrow[lane] = w;
        const int colc = colv_cur;

#define GL(i) const u32* rp##i = hb + ((size_t)(u32)__builtin_amdgcn_readlane(colc, i) << 6); \
              const u32 v##i = rp##i[lane];
        GL(0) GL(1) GL(2) GL(3) GL(4) GL(5) GL(6) GL(7)
        GL(8) GL(9) GL(10) GL(11) GL(12) GL(13) GL(14) GL(15)
#undef GL
        __builtin_amdgcn_sched_barrier(0);

        const float a_n = as_[colv_nxt * H + head];
        __builtin_amdgcn_sched_barrier(0);

        {
            const float4 wa = *(const float4*)(wrow + wbase + 0);
            num0 = fmaf(wa.x, lo16(v0), num0);  num1 = fmaf(wa.x, hi16(v0), num1);
            num0 = fmaf(wa.y, lo16(v1), num0);  num1 = fmaf(wa.y, hi16(v1), num1);
            num0 = fmaf(wa.z, lo16(v2), num0);  num1 = fmaf(wa.z, hi16(v2), num1);
            num0 = fmaf(wa.w, lo16(v3), num0);  num1 = fmaf(wa.w, hi16(v3), num1);
            const float4 wb = *(const float4*)(wrow + wbase + 4);
            num0 = fmaf(wb.x, lo16(v4), num0);  num1 = fmaf(wb.x, hi16(v4), num1);
            num0 = fmaf(wb.y, lo16(v5), num0);  num1 = fmaf(wb.y, hi16(v5), num1);
            num0 = fmaf(wb.z, lo16(v6), num0);  num1 = fmaf(wb.z, hi16(v6), num1);
            num0 = fmaf(wb.w, lo16(v7), num0);  num1 = fmaf(wb.w, hi16(v7), num1);
            const float4 wc = *(const float4*)(wrow + wbase + 8);
            num0 = fmaf(wc.x, lo16(v8), num0);  num1 = fmaf(wc.x, hi16(v8), num1);
            num0 = fmaf(wc.y, lo16(v9), num0);  num1 = fmaf(wc.y, hi16(v9), num1);
            num0 = fmaf(wc.z, lo16(v10), num0); num1 = fmaf(wc.z, hi16(v10), num1);
            num0 = fmaf(wc.w, lo16(v11), num0); num1 = fmaf(wc.w, hi16(v11), num1);
            const float4 wd = *(const float4*)(wrow + wbase + 12);
            num0 = fmaf(wd.x, lo16(v12), num0); num1 = fmaf(wd.x, hi16(v12), num1);
            num0 = fmaf(wd.y, lo16(v13), num0); num1 = fmaf(wd.y, hi16(v13), num1);
            num0 = fmaf(wd.z, lo16(v14), num0); num1 = fmaf(wd.z, hi16(v14), num1);
            num0 = fmaf(wd.w, lo16(v15), num0); num1 = fmaf(wd.w, hi16(v15), num1);
        }

        colv_cur = colv_nxt; colv_nxt = colv_f;
        a_cur = a_n;
        cntc = cntn; cntn = cnt2;
    }

#pragma unroll
    for (int off = 1; off < 16; off <<= 1) den += __shfl_xor(den, off, 64);

    const int c0 = lane * 2;
    const float inv_den = 1.f / (den + SEPS);
    const float2 bi = *(const float2*)(bias + c0);
    float v0 = num0 * inv_den + bi.x;
    float v1 = num1 * inv_den + bi.y;

    float sum = v0 + v1;
#pragma unroll
    for (int off = 32; off; off >>= 1) sum += __shfl_xor(sum, off, 64);
    const float mu = sum * (1.0f / C);
    const float d0 = v0 - mu, d1 = v1 - mu;
    float sq = d0 * d0 + d1 * d1;
#pragma unroll
    for (int off = 32; off; off >>= 1) sq += __shfl_xor(sq, off, 64);
    const float inv = rsqrtf(sq * (1.0f / C) + LEPS);
    const float2 ga = *(const float2*)(gamma + c0);
    const float2 be = *(const float2*)(beta  + c0);
    float y0 = d0 * inv * ga.x + be.x;
    float y1 = d1 * inv * ga.y + be.y;
    y0 = y0 > 0.f ? y0 : __expf(y0) - 1.f;
    y1 = y1 > 0.f ? y1 : __expf(y1) - 1.f;
    float2 o; o.x = y0; o.y = y1;
    *(float2*)(out + (size_t)n * C + c0) = o;
}

extern "C" void kernel_launch(void* const* d_in, const int* in_sizes, int n_in,
                              void* d_out, int out_size, void* d_ws, size_t ws_size,
                              hipStream_t stream)
{
    const float* x     = (const float*)d_in[0];
    const int*   ei    = (const int*)  d_in[1];
    const float* W     = (const float*)d_in[2];
    const float* att_s = (const float*)d_in[3];
    const float* att_d = (const float*)d_in[4];
    const float* bias  = (const float*)d_in[5];
    const float* gamma = (const float*)d_in[6];
    const float* beta  = (const float*)d_in[7];
    float* out = (float*)d_out;

    // ws (~25.8 MB): hb bf16[N*C] | as_ | ad_ | pairs u32[E] | col u16[E+64]
    //              | row_ptr int[N+1] | gcnt u32[NB*256] | gbase u32[NB*256] | tot u32[NB]
    char* p = (char*)d_ws;
    bf16*  hb      = (bf16*)p;   p += (size_t)N * C * sizeof(bf16);
    float* as_     = (float*)p;  p += (size_t)N * H * sizeof(float);
    float* ad_     = (float*)p;  p += (size_t)N * H * sizeof(float);
    u32*   pairs   = (u32*)p;    p += (size_t)E * sizeof(u32);
    u16*   col     = (u16*)p;    p += ((size_t)(E + 64) * sizeof(u16) + 15) & ~(size_t)15;
    int*   row_ptr = (int*)p;    p += ((size_t)(N + 1) * sizeof(int) + 15) & ~(size_t)15;
    u32*   gcnt    = (u32*)p;    p += (size_t)NB * NCH * sizeof(u32);
    u32*   gbase   = (u32*)p;    p += (size_t)NB * NCH * sizeof(u32);
    u32*   tot     = (u32*)p;

    f1_gemm_count<<<GEMM_BLOCKS + NCH, 256, 0, stream>>>(
        x, W, att_s, att_d, ei, (u16*)hb, as_, ad_, gcnt);
    s2a_scan<<<NB, 256, 0, stream>>>(gcnt, gbase, tot);
    kbinB<<<NCH, 256, 0, stream>>>(ei, gbase, tot, pairs);
    kfill2<<<NB, 256, 0, stream>>>(pairs, tot, row_ptr, col);
    // kd split into two half-dispatches (25000 nodes each) so hidden kernels
    // can surface in the profiler's top-5. Numerically identical to one launch.
    kd_agg_ln<<<(25000 * 64) / 256, 256, 0, stream>>>(
        row_ptr, col, (const u32*)hb, as_, ad_, bias, gamma, beta, out, 0);
    kd_agg_ln<<<(25000 * 64) / 256, 256, 0, stream>>>(
        row_ptr, col, (const u32*)hb, as_, ad_, bias, gamma, beta, out, 25000);
}